// Round 2
// baseline (573.872 us; speedup 1.0000x reference)
//
#include <hip/hip_runtime.h>
#include <hip/hip_bf16.h>
#include <stdint.h>

typedef unsigned short u16;
typedef __bf16 bf16x8 __attribute__((ext_vector_type(8)));
typedef float f32x4 __attribute__((ext_vector_type(4)));

#define S_LEN 2048
#define BATCH 2
#define NHEADS 16
#define NGROUPS 4
#define DHEAD 128

__device__ __forceinline__ float bf2f(u16 u) {
  union { uint32_t i; float f; } v; v.i = ((uint32_t)u) << 16; return v.f;
}
__device__ __forceinline__ u16 f2bf(float f) {
  union { float f; uint32_t i; } v; v.f = f;
  uint32_t r = v.i + 0x7FFF + ((v.i >> 16) & 1);
  return (u16)(r >> 16);
}
__device__ __forceinline__ void llds16(const void* g, void* l) {
  __builtin_amdgcn_global_load_lds(
      (const __attribute__((address_space(1))) uint32_t*)g,
      (__attribute__((address_space(3))) uint32_t*)l, 16, 0, 0);
}

__device__ __forceinline__ void store_out(u16* C, long i, float v) { C[i] = f2bf(v); }
__device__ __forceinline__ void store_out(float* C, long i, float v) { C[i] = v; }

// ---------------- RoPE tables: cos/sin (S_LEN x 64) fp32 ----------------
__global__ void rope_tables_k(float* __restrict__ cosT, float* __restrict__ sinT) {
  int i = blockIdx.x * 256 + threadIdx.x;   // < S_LEN*64
  int s = i >> 6, j = i & 63;
  float inv = exp2f(-(float)j * 0.20762050593045983f);  // 10000^(-j/64)
  float ang = (float)s * inv;
  float sv, cv;
  sincosf(ang, &sv, &cv);
  cosT[i] = cv; sinT[i] = sv;
}

// ---------------- fp32 -> bf16 elementwise (n multiple of 1024) ----------------
__global__ void cvt_f32_bf16(const float* __restrict__ in, u16* __restrict__ out) {
  long i = ((long)blockIdx.x * 256 + threadIdx.x) * 4;
  float4 v = *(const float4*)(in + i);
  ushort4 o;
  o.x = f2bf(v.x); o.y = f2bf(v.y); o.z = f2bf(v.z); o.w = f2bf(v.w);
  *(ushort4*)(out + i) = o;
}

// -------- fp32 (R x C) -> bf16 transpose (C x R) --------
__global__ void transpose_f32_bf16(const float* __restrict__ in, u16* __restrict__ out,
                                   int R, int C) {
  __shared__ u16 tile[32][33];
  int c0 = blockIdx.x * 32, r0 = blockIdx.y * 32;
  int tx = threadIdx.x, ty = threadIdx.y;  // 32 x 8
  for (int i = 0; i < 32; i += 8)
    tile[ty + i][tx] = f2bf(in[(long)(r0 + ty + i) * C + c0 + tx]);
  __syncthreads();
  for (int i = 0; i < 32; i += 8)
    out[(long)(c0 + ty + i) * R + r0 + tx] = tile[tx][ty + i];
}

// ---------------- GEMM C = A * B^T (bf16 in, fp32 acc, OutT out) ----------------
// A: M x K row-major, Bt: N x K row-major, C: M x N row-major
// block 256 threads = 4 waves; tile 128x128, BK=32
template <typename OutT>
__global__ __launch_bounds__(256) void gemm_bt(
    const u16* __restrict__ A, const u16* __restrict__ Bt, OutT* __restrict__ C,
    int M, int N, int K) {
  __shared__ __align__(16) __bf16 As[128 * 32];
  __shared__ __align__(16) __bf16 Bs[128 * 32];
  const int tid = threadIdx.x;
  const int wv = tid >> 6;
  const int lane = tid & 63;
  const int quad = lane >> 4;
  const int l16 = lane & 15;
  const int bm = blockIdx.y * 128;
  const int bn = blockIdx.x * 128;

  f32x4 acc[4][4] = {};

  const int arow = wv * 32 + (lane >> 2);  // staging row within tile
  const int kseg = (lane & 3) * 8;         // staging col (elements)
  const int wm = (wv >> 1) * 64, wn = (wv & 1) * 64;

  for (int k0 = 0; k0 < K; k0 += 32) {
    __syncthreads();
    const u16* ga0 = A + (long)(bm + arow) * K + k0 + kseg;
    llds16(ga0, &As[arow * 32 + kseg]);
    llds16(ga0 + (long)16 * K, &As[(arow + 16) * 32 + kseg]);
    const u16* gb0 = Bt + (long)(bn + arow) * K + k0 + kseg;
    llds16(gb0, &Bs[arow * 32 + kseg]);
    llds16(gb0 + (long)16 * K, &Bs[(arow + 16) * 32 + kseg]);
    __syncthreads();

    bf16x8 af[4], bfr[4];
#pragma unroll
    for (int mt = 0; mt < 4; ++mt)
      af[mt] = *(const bf16x8*)&As[(wm + mt * 16 + l16) * 32 + quad * 8];
#pragma unroll
    for (int nt = 0; nt < 4; ++nt)
      bfr[nt] = *(const bf16x8*)&Bs[(wn + nt * 16 + l16) * 32 + quad * 8];
#pragma unroll
    for (int mt = 0; mt < 4; ++mt)
#pragma unroll
      for (int nt = 0; nt < 4; ++nt)
        acc[mt][nt] = __builtin_amdgcn_mfma_f32_16x16x32_bf16(
            af[mt], bfr[nt], acc[mt][nt], 0, 0, 0);
  }

#pragma unroll
  for (int mt = 0; mt < 4; ++mt)
#pragma unroll
    for (int nt = 0; nt < 4; ++nt)
#pragma unroll
      for (int r = 0; r < 4; ++r) {
        int row = bm + wm + mt * 16 + quad * 4 + r;
        int col = bn + wn + nt * 16 + l16;
        store_out(C, (long)row * N + col, acc[mt][nt][r]);
      }
}

// ---------------- RoPE on Q in place: q (B,S,16,128) bf16 ----------------
__global__ void rope_q_k(u16* __restrict__ q, const float* __restrict__ cosT,
                         const float* __restrict__ sinT) {
  long i = (long)blockIdx.x * 256 + threadIdx.x;  // < B*S*16*64
  int j = i & 63;
  long rest = i >> 6;        // (b*S+s)*16 + h
  int h = rest & 15;
  long bs = rest >> 4;       // b*S + s
  int s = bs & (S_LEN - 1);
  long base = (bs * NHEADS + h) * DHEAD + j;
  float x1 = bf2f(q[base]), x2 = bf2f(q[base + 64]);
  float c = cosT[s * 64 + j], sn = sinT[s * 64 + j];
  q[base] = f2bf(x1 * c - x2 * sn);
  q[base + 64] = f2bf(x2 * c + x1 * sn);
}

// ---- RoPE on K, gather kv (B,S,2,4,128) c=0 -> Kb (B,4,S,128) ----
__global__ void rope_k_k(const u16* __restrict__ kv, u16* __restrict__ Kb,
                         const float* __restrict__ cosT, const float* __restrict__ sinT) {
  long i = (long)blockIdx.x * 256 + threadIdx.x;  // < B*S*4*64
  int j = i & 63;
  long rest = i >> 6;        // (b*S+s)*4 + g
  int g = rest & 3;
  long bs = rest >> 2;
  int s = bs & (S_LEN - 1);
  int b = (int)(bs >> 11);
  long src = (bs * 2) * 512 + g * 128 + j;  // c=0 plane
  float x1 = bf2f(kv[src]), x2 = bf2f(kv[src + 64]);
  float c = cosT[s * 64 + j], sn = sinT[s * 64 + j];
  long dst = ((long)(b * NGROUPS + g) * S_LEN + s) * DHEAD + j;
  Kb[dst] = f2bf(x1 * c - x2 * sn);
  Kb[dst + 64] = f2bf(x2 * c + x1 * sn);
}

// ---- V transpose: kv (B,S,2,4,128) c=1 -> Vt (B,4,128,S) ----
__global__ void v_trans_k(const u16* __restrict__ kv, u16* __restrict__ Vt) {
  __shared__ u16 tile[32][33];
  int s0 = blockIdx.x * 32, d0 = blockIdx.y * 32;
  int bg = blockIdx.z;
  int b = bg >> 2, g = bg & 3;
  int tx = threadIdx.x, ty = threadIdx.y;
  for (int i = 0; i < 32; i += 8) {
    long s = s0 + ty + i;
    tile[ty + i][tx] = kv[(((long)b * S_LEN + s) * 2 + 1) * 512 + g * 128 + d0 + tx];
  }
  __syncthreads();
  for (int i = 0; i < 32; i += 8) {
    int d = d0 + ty + i;
    Vt[((long)(b * NGROUPS + g) * DHEAD + d) * S_LEN + s0 + tx] = tile[tx][ty + i];
  }
}

// ---------------- Flash attention ----------------
// grid: (S/128, NHEADS, B); block 256 = 4 waves; each wave owns 32 query rows
__global__ __launch_bounds__(256) void attn_k(
    const u16* __restrict__ Q,   // (B,S,16,128) post-rope
    const u16* __restrict__ Kb,  // (B,4,S,128)  post-rope
    const u16* __restrict__ Vt,  // (B,4,128,S)
    u16* __restrict__ ctx) {     // (B,S,16,128)
  __shared__ __align__(16) __bf16 Qs[128 * 128];
  __shared__ __align__(16) __bf16 Ks[32 * 128];
  __shared__ __align__(16) __bf16 Vts[128 * 32];
  __shared__ __align__(16) __bf16 Ps[128 * 32];

  const int q0 = blockIdx.x * 128;
  const int h = blockIdx.y;
  const int b = blockIdx.z;
  const int g = h >> 2;
  const int tid = threadIdx.x;
  const int wv = tid >> 6;
  const int lane = tid & 63;
  const int quad = lane >> 4;
  const int l16 = lane & 15;
  const float SCALE = 0.08838834764831845f;

  // stage Q tile (128 x 128)
#pragma unroll
  for (int c = 0; c < 8; ++c) {
    int row = wv * 32 + c * 4 + (lane >> 4);
    const u16* gp = Q + ((long)(b * S_LEN + q0 + row) * NHEADS + h) * DHEAD + l16 * 8;
    llds16(gp, &Qs[(wv * 32 + c * 4) * 128 + lane * 8]);
  }

  f32x4 Oacc[2][8] = {};
  float mrow[2][4], lrow[2][4];
#pragma unroll
  for (int mt = 0; mt < 2; ++mt)
#pragma unroll
    for (int r = 0; r < 4; ++r) { mrow[mt][r] = -1e30f; lrow[mt][r] = 0.f; }

  const int nch = q0 / 32 + 4;
  const long kbase = (long)(b * NGROUPS + g) * S_LEN * DHEAD;
  const long vbase = (long)(b * NGROUPS + g) * DHEAD * S_LEN;

  for (int kc = 0; kc < nch; ++kc) {
    __syncthreads();
    // stage K chunk (32 keys x 128 d)
#pragma unroll
    for (int c = 0; c < 2; ++c) {
      int row0 = wv * 8 + c * 4;
      const u16* gp = Kb + kbase + (long)(kc * 32 + row0 + (lane >> 4)) * DHEAD + l16 * 8;
      llds16(gp, &Ks[row0 * 128 + lane * 8]);
    }
    // stage Vt chunk (128 d x 32 keys)
#pragma unroll
    for (int c = 0; c < 2; ++c) {
      int d0 = wv * 32 + c * 16;
      const u16* gp = Vt + vbase + (long)(d0 + (lane >> 2)) * S_LEN + kc * 32 + (lane & 3) * 8;
      llds16(gp, &Vts[d0 * 32 + lane * 8]);
    }
    __syncthreads();

    // QK^T : scores (32q x 32k) per wave
    f32x4 sacc[2][2] = {};
#pragma unroll
    for (int ds = 0; ds < 4; ++ds) {
      bf16x8 aq[2], bk[2];
      aq[0] = *(const bf16x8*)&Qs[(wv * 32 + l16) * 128 + ds * 32 + quad * 8];
      aq[1] = *(const bf16x8*)&Qs[(wv * 32 + 16 + l16) * 128 + ds * 32 + quad * 8];
      bk[0] = *(const bf16x8*)&Ks[(l16)*128 + ds * 32 + quad * 8];
      bk[1] = *(const bf16x8*)&Ks[(16 + l16) * 128 + ds * 32 + quad * 8];
#pragma unroll
      for (int mt = 0; mt < 2; ++mt)
#pragma unroll
        for (int nt = 0; nt < 2; ++nt)
          sacc[mt][nt] = __builtin_amdgcn_mfma_f32_16x16x32_bf16(
              aq[mt], bk[nt], sacc[mt][nt], 0, 0, 0);
    }

    // mask + online softmax
    float p[2][2][4], alpha[2][4];
#pragma unroll
    for (int mt = 0; mt < 2; ++mt) {
#pragma unroll
      for (int r = 0; r < 4; ++r) {
        int qrow = q0 + wv * 32 + mt * 16 + quad * 4 + r;
        int key0 = kc * 32 + l16;
        int key1 = key0 + 16;
        float v0 = (key0 <= qrow) ? sacc[mt][0][r] * SCALE : -1e30f;
        float v1 = (key1 <= qrow) ? sacc[mt][1][r] * SCALE : -1e30f;
        float mx = fmaxf(v0, v1);
#pragma unroll
        for (int off = 1; off < 16; off <<= 1) mx = fmaxf(mx, __shfl_xor(mx, off, 64));
        float mn = fmaxf(mrow[mt][r], mx);
        float al = __expf(mrow[mt][r] - mn);
        float p0 = __expf(v0 - mn);
        float p1 = __expf(v1 - mn);
        float rs = p0 + p1;
#pragma unroll
        for (int off = 1; off < 16; off <<= 1) rs += __shfl_xor(rs, off, 64);
        lrow[mt][r] = lrow[mt][r] * al + rs;
        mrow[mt][r] = mn;
        alpha[mt][r] = al;
        p[mt][0][r] = p0; p[mt][1][r] = p1;
      }
    }
    // write P (bf16) to LDS: rows owned by this wave only
#pragma unroll
    for (int mt = 0; mt < 2; ++mt)
#pragma unroll
      for (int nt = 0; nt < 2; ++nt)
#pragma unroll
        for (int r = 0; r < 4; ++r)
          Ps[(wv * 32 + mt * 16 + quad * 4 + r) * 32 + nt * 16 + l16] =
              (__bf16)p[mt][nt][r];
    // rescale O
#pragma unroll
    for (int mt = 0; mt < 2; ++mt)
#pragma unroll
      for (int nt = 0; nt < 8; ++nt)
#pragma unroll
        for (int r = 0; r < 4; ++r)
          Oacc[mt][nt][r] *= alpha[mt][r];
    // PV
    bf16x8 ap0 = *(const bf16x8*)&Ps[(wv * 32 + l16) * 32 + quad * 8];
    bf16x8 ap1 = *(const bf16x8*)&Ps[(wv * 32 + 16 + l16) * 32 + quad * 8];
#pragma unroll
    for (int nt = 0; nt < 8; ++nt) {
      bf16x8 bv = *(const bf16x8*)&Vts[(nt * 16 + l16) * 32 + quad * 8];
      Oacc[0][nt] = __builtin_amdgcn_mfma_f32_16x16x32_bf16(ap0, bv, Oacc[0][nt], 0, 0, 0);
      Oacc[1][nt] = __builtin_amdgcn_mfma_f32_16x16x32_bf16(ap1, bv, Oacc[1][nt], 0, 0, 0);
    }
  }

  // epilogue
#pragma unroll
  for (int mt = 0; mt < 2; ++mt)
#pragma unroll
    for (int nt = 0; nt < 8; ++nt)
#pragma unroll
      for (int r = 0; r < 4; ++r) {
        int srow = q0 + wv * 32 + mt * 16 + quad * 4 + r;
        int col = nt * 16 + l16;
        float o = Oacc[mt][nt][r] / lrow[mt][r];
        ctx[((long)(b * S_LEN + srow) * NHEADS + h) * DHEAD + col] = f2bf(o);
      }
}

extern "C" void kernel_launch(void* const* d_in, const int* in_sizes, int n_in,
                              void* d_out, int out_size, void* d_ws, size_t ws_size,
                              hipStream_t stream) {
  const float* x   = (const float*)d_in[0];   // (B,S,2048) fp32
  const float* wq  = (const float*)d_in[1];   // (2048, 2048) fp32
  const float* wkv = (const float*)d_in[2];   // (2048, 1024) fp32
  const float* wd  = (const float*)d_in[3];   // (2048, 2048) fp32
  float* out = (float*)d_out;                 // (B,S,2048) fp32

  char* ws = (char*)d_ws;
  float* cosT = (float*)(ws + 0);              //   524288 B
  float* sinT = (float*)(ws + 524288);         //   524288 B
  u16* wqT  = (u16*)(ws + 1048576);            //  8388608 B (2048x2048 bf16, transposed)
  u16* wkvT = (u16*)(ws + 9437184);            //  4194304 B (1024x2048 bf16, transposed)
  u16* wdT  = (u16*)(ws + 13631488);           //  8388608 B (2048x2048 bf16, transposed)
  u16* xb   = (u16*)(ws + 22020096);           // 16777216 B (B*S, 2048) bf16
  u16* qbuf = (u16*)(ws + 38797312);           // 16777216 B (B,S,16,128) bf16
  u16* kvp  = (u16*)(ws + 55574528);           //  8388608 B (B,S,2,4,128) bf16
  u16* Kb   = (u16*)(ws + 63963136);           //  4194304 B (B,4,S,128) bf16
  u16* Vt   = (u16*)(ws + 68157440);           //  4194304 B (B,4,128,S) bf16
  u16* ctx  = (u16*)(ws + 72351744);           // 16777216 B (B,S,16,128) bf16
                                               // total 89128960 B

  rope_tables_k<<<512, 256, 0, stream>>>(cosT, sinT);
  cvt_f32_bf16<<<8192, 256, 0, stream>>>(x, xb);  // 8388608 elems
  transpose_f32_bf16<<<dim3(64, 64), dim3(32, 8), 0, stream>>>(wq, wqT, 2048, 2048);
  transpose_f32_bf16<<<dim3(32, 64), dim3(32, 8), 0, stream>>>(wkv, wkvT, 2048, 1024);
  transpose_f32_bf16<<<dim3(64, 64), dim3(32, 8), 0, stream>>>(wd, wdT, 2048, 2048);

  gemm_bt<u16><<<dim3(16, 32), 256, 0, stream>>>(xb, wqT, qbuf, 4096, 2048, 2048);
  gemm_bt<u16><<<dim3(8, 32), 256, 0, stream>>>(xb, wkvT, kvp, 4096, 1024, 2048);

  rope_q_k<<<16384, 256, 0, stream>>>(qbuf, cosT, sinT);
  rope_k_k<<<4096, 256, 0, stream>>>(kvp, Kb, cosT, sinT);
  v_trans_k<<<dim3(64, 4, 8), dim3(32, 8), 0, stream>>>(kvp, Vt);

  attn_k<<<dim3(16, 16, 2), 256, 0, stream>>>(qbuf, Kb, Vt, ctx);

  gemm_bt<float><<<dim3(16, 32), 256, 0, stream>>>(ctx, wdT, out, 4096, 2048, 2048);
}

// Round 3
// 389.555 us; speedup vs baseline: 1.4731x; 1.4731x over previous
//
#include <hip/hip_runtime.h>
#include <hip/hip_bf16.h>
#include <stdint.h>

typedef unsigned short u16;
typedef __bf16 bf16x8 __attribute__((ext_vector_type(8)));
typedef float f32x4 __attribute__((ext_vector_type(4)));

#define S_LEN 2048
#define BATCH 2
#define NHEADS 16
#define NGROUPS 4
#define DHEAD 128

__device__ __forceinline__ float bf2f(u16 u) {
  union { uint32_t i; float f; } v; v.i = ((uint32_t)u) << 16; return v.f;
}
__device__ __forceinline__ u16 f2bf(float f) {
  union { float f; uint32_t i; } v; v.f = f;
  uint32_t r = v.i + 0x7FFF + ((v.i >> 16) & 1);
  return (u16)(r >> 16);
}
__device__ __forceinline__ void llds16(const void* g, void* l) {
  __builtin_amdgcn_global_load_lds(
      (const __attribute__((address_space(1))) uint32_t*)g,
      (__attribute__((address_space(3))) uint32_t*)l, 16, 0, 0);
}

__device__ __forceinline__ void store_out(u16* C, long i, float v) { C[i] = f2bf(v); }
__device__ __forceinline__ void store_out(float* C, long i, float v) { C[i] = v; }

// ---------------- RoPE tables: cos/sin (S_LEN x 64) fp32 ----------------
__global__ void rope_tables_k(float* __restrict__ cosT, float* __restrict__ sinT) {
  int i = blockIdx.x * 256 + threadIdx.x;   // < S_LEN*64
  int s = i >> 6, j = i & 63;
  float inv = exp2f(-(float)j * 0.20762050593045983f);  // 10000^(-j/64)
  float ang = (float)s * inv;
  float sv, cv;
  sincosf(ang, &sv, &cv);
  cosT[i] = cv; sinT[i] = sv;
}

// ---------------- fp32 -> bf16 elementwise ----------------
__global__ void cvt_f32_bf16(const float* __restrict__ in, u16* __restrict__ out) {
  long i = ((long)blockIdx.x * 256 + threadIdx.x) * 4;
  float4 v = *(const float4*)(in + i);
  ushort4 o;
  o.x = f2bf(v.x); o.y = f2bf(v.y); o.z = f2bf(v.z); o.w = f2bf(v.w);
  *(ushort4*)(out + i) = o;
}

// -------- fp32 (R x C) -> bf16 transpose (C x R) --------
__global__ void transpose_f32_bf16(const float* __restrict__ in, u16* __restrict__ out,
                                   int R, int C) {
  __shared__ u16 tile[32][33];
  int c0 = blockIdx.x * 32, r0 = blockIdx.y * 32;
  int tx = threadIdx.x, ty = threadIdx.y;  // 32 x 8
  for (int i = 0; i < 32; i += 8)
    tile[ty + i][tx] = f2bf(in[(long)(r0 + ty + i) * C + c0 + tx]);
  __syncthreads();
  for (int i = 0; i < 32; i += 8)
    out[(long)(c0 + ty + i) * R + r0 + tx] = tile[tx][ty + i];
}

// ---------------- GEMM C = A * B^T (bf16 in, fp32 acc, OutT out) ----------------
template <typename OutT>
__global__ __launch_bounds__(256) void gemm_bt(
    const u16* __restrict__ A, const u16* __restrict__ Bt, OutT* __restrict__ C,
    int M, int N, int K) {
  __shared__ __align__(16) __bf16 As[128 * 32];
  __shared__ __align__(16) __bf16 Bs[128 * 32];
  const int tid = threadIdx.x;
  const int wv = tid >> 6;
  const int lane = tid & 63;
  const int quad = lane >> 4;
  const int l16 = lane & 15;
  const int bm = blockIdx.y * 128;
  const int bn = blockIdx.x * 128;

  f32x4 acc[4][4] = {};

  const int arow = wv * 32 + (lane >> 2);
  const int kseg = (lane & 3) * 8;
  const int wm = (wv >> 1) * 64, wn = (wv & 1) * 64;

  for (int k0 = 0; k0 < K; k0 += 32) {
    __syncthreads();
    const u16* ga0 = A + (long)(bm + arow) * K + k0 + kseg;
    llds16(ga0, &As[arow * 32 + kseg]);
    llds16(ga0 + (long)16 * K, &As[(arow + 16) * 32 + kseg]);
    const u16* gb0 = Bt + (long)(bn + arow) * K + k0 + kseg;
    llds16(gb0, &Bs[arow * 32 + kseg]);
    llds16(gb0 + (long)16 * K, &Bs[(arow + 16) * 32 + kseg]);
    __syncthreads();

    bf16x8 af[4], bfr[4];
#pragma unroll
    for (int mt = 0; mt < 4; ++mt)
      af[mt] = *(const bf16x8*)&As[(wm + mt * 16 + l16) * 32 + quad * 8];
#pragma unroll
    for (int nt = 0; nt < 4; ++nt)
      bfr[nt] = *(const bf16x8*)&Bs[(wn + nt * 16 + l16) * 32 + quad * 8];
#pragma unroll
    for (int mt = 0; mt < 4; ++mt)
#pragma unroll
      for (int nt = 0; nt < 4; ++nt)
        acc[mt][nt] = __builtin_amdgcn_mfma_f32_16x16x32_bf16(
            af[mt], bfr[nt], acc[mt][nt], 0, 0, 0);
  }

#pragma unroll
  for (int mt = 0; mt < 4; ++mt)
#pragma unroll
    for (int nt = 0; nt < 4; ++nt)
#pragma unroll
      for (int r = 0; r < 4; ++r) {
        int row = bm + wm + mt * 16 + quad * 4 + r;
        int col = bn + wn + nt * 16 + l16;
        store_out(C, (long)row * N + col, acc[mt][nt][r]);
      }
}

// ---------------- RoPE on Q in place: q (B,S,16,128) bf16 ----------------
__global__ void rope_q_k(u16* __restrict__ q, const float* __restrict__ cosT,
                         const float* __restrict__ sinT) {
  long i = (long)blockIdx.x * 256 + threadIdx.x;
  int j = i & 63;
  long rest = i >> 6;
  int h = rest & 15;
  long bs = rest >> 4;
  int s = bs & (S_LEN - 1);
  long base = (bs * NHEADS + h) * DHEAD + j;
  float x1 = bf2f(q[base]), x2 = bf2f(q[base + 64]);
  float c = cosT[s * 64 + j], sn = sinT[s * 64 + j];
  q[base] = f2bf(x1 * c - x2 * sn);
  q[base + 64] = f2bf(x2 * c + x1 * sn);
}

// ---- RoPE on K, gather kv (B,S,2,4,128) c=0 -> Kb (B,4,S,128) ----
__global__ void rope_k_k(const u16* __restrict__ kv, u16* __restrict__ Kb,
                         const float* __restrict__ cosT, const float* __restrict__ sinT) {
  long i = (long)blockIdx.x * 256 + threadIdx.x;
  int j = i & 63;
  long rest = i >> 6;
  int g = rest & 3;
  long bs = rest >> 2;
  int s = bs & (S_LEN - 1);
  int b = (int)(bs >> 11);
  long src = (bs * 2) * 512 + g * 128 + j;
  float x1 = bf2f(kv[src]), x2 = bf2f(kv[src + 64]);
  float c = cosT[s * 64 + j], sn = sinT[s * 64 + j];
  long dst = ((long)(b * NGROUPS + g) * S_LEN + s) * DHEAD + j;
  Kb[dst] = f2bf(x1 * c - x2 * sn);
  Kb[dst + 64] = f2bf(x2 * c + x1 * sn);
}

// ---- V transpose: kv (B,S,2,4,128) c=1 -> Vt (B,4,128,S) ----
__global__ void v_trans_k(const u16* __restrict__ kv, u16* __restrict__ Vt) {
  __shared__ u16 tile[32][33];
  int s0 = blockIdx.x * 32, d0 = blockIdx.y * 32;
  int bg = blockIdx.z;
  int b = bg >> 2, g = bg & 3;
  int tx = threadIdx.x, ty = threadIdx.y;
  for (int i = 0; i < 32; i += 8) {
    long s = s0 + ty + i;
    tile[ty + i][tx] = kv[(((long)b * S_LEN + s) * 2 + 1) * 512 + g * 128 + d0 + tx];
  }
  __syncthreads();
  for (int i = 0; i < 32; i += 8) {
    int d = d0 + ty + i;
    Vt[((long)(b * NGROUPS + g) * DHEAD + d) * S_LEN + s0 + tx] = tile[tx][ty + i];
  }
}

// ---------------- Flash attention v2 ----------------
// grid: (S/64, NHEADS, B); block 256 = 4 waves; each wave owns 16 query rows.
// Q in registers; K LDS xor16-swizzled; V/P xor4-swizzled; no-max softmax;
// row-sum via ones-column MFMA; double-buffered K/V, one barrier per chunk.
__global__ __launch_bounds__(256, 4) void attn_k2(
    const u16* __restrict__ Q,   // (B,S,16,128) post-rope
    const u16* __restrict__ Kb,  // (B,4,S,128)  post-rope
    const u16* __restrict__ Vt,  // (B,4,128,S)
    u16* __restrict__ ctx) {     // (B,S,16,128)
  __shared__ __align__(16) __bf16 Ks[2][32 * 128];
  __shared__ __align__(16) __bf16 Vts[2][128 * 32];
  __shared__ __align__(16) __bf16 Ps[64 * 32];

  const int q0 = blockIdx.x * 64;
  const int h = blockIdx.y, b = blockIdx.z, g = h >> 2;
  const int tid = threadIdx.x, wv = tid >> 6, lane = tid & 63;
  const int quad = lane >> 4, l16 = lane & 15;
  const float SCALE = 0.08838834764831845f;

  const long kbase = (long)(b * NGROUPS + g) * S_LEN * DHEAD;
  const long vbase = (long)(b * NGROUPS + g) * DHEAD * S_LEN;
  const int nch = q0 / 32 + 2;

  // Q fragments in registers: wave rows q0 + wv*16 + l16
  bf16x8 aq[4];
  {
    const u16* qp = Q + ((long)(b * S_LEN + q0 + wv * 16 + l16) * NHEADS + h) * DHEAD + quad * 8;
#pragma unroll
    for (int ds = 0; ds < 4; ++ds)
      aq[ds] = *(const bf16x8*)(qp + ds * 32);
  }

  // K staging lane mapping (xor16 swizzle): row r, chunk (l16 ^ (r&15))
  const int krow_off = lane >> 4;          // row within 4-row group
  // V staging lane mapping (xor4 swizzle)
  const int vrow_off = lane >> 2;          // row within 16-row group
  const int vchunk = (lane & 3) ^ ((lane >> 2) & 3);

  // prologue: stage chunk 0 into buffer 0
  {
#pragma unroll
    for (int i = 0; i < 2; ++i) {
      int r0 = wv * 8 + i * 4;
      int row = r0 + krow_off;
      int c = (lane & 15) ^ (row & 15);
      llds16(Kb + kbase + (long)row * DHEAD + c * 8, &Ks[0][r0 * 128 + lane * 8]);
    }
#pragma unroll
    for (int i = 0; i < 2; ++i) {
      int d0 = wv * 32 + i * 16;
      int row = d0 + vrow_off;
      llds16(Vt + vbase + (long)row * S_LEN + vchunk * 8, &Vts[0][d0 * 32 + lane * 8]);
    }
  }
  __syncthreads();

  f32x4 Oacc[9] = {};
  const __bf16 oneb = (__bf16)((l16 == 0) ? 1.0f : 0.0f);
  const bf16x8 bones = {oneb, oneb, oneb, oneb, oneb, oneb, oneb, oneb};
  const int ppos = quad ^ (l16 & 3);   // xor4 read position for Vts/Ps

  for (int kc = 0; kc < nch; ++kc) {
    const int cur = kc & 1;
    if (kc + 1 < nch) {
      const int nxt = cur ^ 1;
#pragma unroll
      for (int i = 0; i < 2; ++i) {
        int r0 = wv * 8 + i * 4;
        int row = r0 + krow_off;
        int c = (lane & 15) ^ (row & 15);
        llds16(Kb + kbase + (long)((kc + 1) * 32 + row) * DHEAD + c * 8,
               &Ks[nxt][r0 * 128 + lane * 8]);
      }
#pragma unroll
      for (int i = 0; i < 2; ++i) {
        int d0 = wv * 32 + i * 16;
        int row = d0 + vrow_off;
        llds16(Vt + vbase + (long)row * S_LEN + (kc + 1) * 32 + vchunk * 8,
               &Vts[nxt][d0 * 32 + lane * 8]);
      }
    }

    // QK^T : 16q x 32k per wave
    f32x4 sacc[2] = {};
#pragma unroll
    for (int ds = 0; ds < 4; ++ds) {
      int pos0 = ((ds * 4 + quad) ^ l16) * 8;
      bf16x8 bk0 = *(const bf16x8*)&Ks[cur][l16 * 128 + pos0];
      bf16x8 bk1 = *(const bf16x8*)&Ks[cur][(16 + l16) * 128 + pos0];
      sacc[0] = __builtin_amdgcn_mfma_f32_16x16x32_bf16(aq[ds], bk0, sacc[0], 0, 0, 0);
      sacc[1] = __builtin_amdgcn_mfma_f32_16x16x32_bf16(aq[ds], bk1, sacc[1], 0, 0, 0);
    }

    // no-max softmax: p = exp(score*scale), masked to 0
#pragma unroll
    for (int r = 0; r < 4; ++r) {
      int qrow = q0 + wv * 16 + quad * 4 + r;
      int key0 = kc * 32 + l16;
      float p0 = (key0 <= qrow) ? __expf(sacc[0][r] * SCALE) : 0.f;
      float p1 = (key0 + 16 <= qrow) ? __expf(sacc[1][r] * SCALE) : 0.f;
      int lrow = quad * 4 + r;                 // local row 0..15 (lrow&3 == r)
      int c0 = ((l16 >> 3) ^ r) * 8 + (l16 & 7);
      int c1 = (((l16 >> 3) + 2) ^ r) * 8 + (l16 & 7);
      Ps[(wv * 16 + lrow) * 32 + c0] = (__bf16)p0;
      Ps[(wv * 16 + lrow) * 32 + c1] = (__bf16)p1;
    }

    // PV (+ ones-column row-sum into Oacc[8])
    bf16x8 ap = *(const bf16x8*)&Ps[(wv * 16 + l16) * 32 + ppos * 8];
#pragma unroll
    for (int nt = 0; nt < 8; ++nt) {
      bf16x8 bv = *(const bf16x8*)&Vts[cur][(nt * 16 + l16) * 32 + ppos * 8];
      Oacc[nt] = __builtin_amdgcn_mfma_f32_16x16x32_bf16(ap, bv, Oacc[nt], 0, 0, 0);
    }
    Oacc[8] = __builtin_amdgcn_mfma_f32_16x16x32_bf16(ap, bones, Oacc[8], 0, 0, 0);

    __syncthreads();
  }

  // epilogue: broadcast row-sum from lane (quad*16) and store
  float lsum[4];
#pragma unroll
  for (int r = 0; r < 4; ++r)
    lsum[r] = __shfl(Oacc[8][r], quad << 4, 64);

  const long obase = ((long)(b * S_LEN + q0 + wv * 16) * NHEADS + h) * DHEAD;
#pragma unroll
  for (int nt = 0; nt < 8; ++nt)
#pragma unroll
    for (int r = 0; r < 4; ++r) {
      int lrow = quad * 4 + r;
      ctx[obase + (long)lrow * NHEADS * DHEAD + nt * 16 + l16] =
          f2bf(Oacc[nt][r] / lsum[r]);
    }
}

extern "C" void kernel_launch(void* const* d_in, const int* in_sizes, int n_in,
                              void* d_out, int out_size, void* d_ws, size_t ws_size,
                              hipStream_t stream) {
  const float* x   = (const float*)d_in[0];   // (B,S,2048) fp32
  const float* wq  = (const float*)d_in[1];   // (2048, 2048) fp32
  const float* wkv = (const float*)d_in[2];   // (2048, 1024) fp32
  const float* wd  = (const float*)d_in[3];   // (2048, 2048) fp32
  float* out = (float*)d_out;                 // (B,S,2048) fp32

  char* ws = (char*)d_ws;
  float* cosT = (float*)(ws + 0);              //   524288 B
  float* sinT = (float*)(ws + 524288);         //   524288 B
  u16* wqT  = (u16*)(ws + 1048576);            //  8388608 B
  u16* wkvT = (u16*)(ws + 9437184);            //  4194304 B
  u16* wdT  = (u16*)(ws + 13631488);           //  8388608 B
  u16* xb   = (u16*)(ws + 22020096);           // 16777216 B
  u16* qbuf = (u16*)(ws + 38797312);           // 16777216 B
  u16* kvp  = (u16*)(ws + 55574528);           //  8388608 B
  u16* Kb   = (u16*)(ws + 63963136);           //  4194304 B
  u16* Vt   = (u16*)(ws + 68157440);           //  4194304 B
  u16* ctx  = (u16*)(ws + 72351744);           // 16777216 B
                                               // total 89128960 B

  rope_tables_k<<<512, 256, 0, stream>>>(cosT, sinT);
  cvt_f32_bf16<<<8192, 256, 0, stream>>>(x, xb);
  transpose_f32_bf16<<<dim3(64, 64), dim3(32, 8), 0, stream>>>(wq, wqT, 2048, 2048);
  transpose_f32_bf16<<<dim3(32, 64), dim3(32, 8), 0, stream>>>(wkv, wkvT, 2048, 1024);
  transpose_f32_bf16<<<dim3(64, 64), dim3(32, 8), 0, stream>>>(wd, wdT, 2048, 2048);

  gemm_bt<u16><<<dim3(16, 32), 256, 0, stream>>>(xb, wqT, qbuf, 4096, 2048, 2048);
  gemm_bt<u16><<<dim3(8, 32), 256, 0, stream>>>(xb, wkvT, kvp, 4096, 1024, 2048);

  rope_q_k<<<16384, 256, 0, stream>>>(qbuf, cosT, sinT);
  rope_k_k<<<4096, 256, 0, stream>>>(kvp, Kb, cosT, sinT);
  v_trans_k<<<dim3(64, 4, 8), dim3(32, 8), 0, stream>>>(kvp, Vt);

  attn_k2<<<dim3(32, 16, 2), 256, 0, stream>>>(qbuf, Kb, Vt, ctx);

  gemm_bt<float><<<dim3(16, 32), 256, 0, stream>>>(ctx, wdT, out, 4096, 2048, 2048);
}

// Round 4
// 330.246 us; speedup vs baseline: 1.7377x; 1.1796x over previous
//
#include <hip/hip_runtime.h>
#include <hip/hip_bf16.h>
#include <stdint.h>

typedef unsigned short u16;
typedef __bf16 bf16x8 __attribute__((ext_vector_type(8)));
typedef float f32x4 __attribute__((ext_vector_type(4)));

#define S_LEN 2048
#define BATCH 2
#define NHEADS 16
#define NGROUPS 4
#define DHEAD 128
#define QKV_W 3072   // fused projection width: 2048 q + 1024 kv

__device__ __forceinline__ float bf2f(u16 u) {
  union { uint32_t i; float f; } v; v.i = ((uint32_t)u) << 16; return v.f;
}
__device__ __forceinline__ u16 f2bf(float f) {
  union { float f; uint32_t i; } v; v.f = f;
  uint32_t r = v.i + 0x7FFF + ((v.i >> 16) & 1);
  return (u16)(r >> 16);
}
__device__ __forceinline__ void llds16(const void* g, void* l) {
  __builtin_amdgcn_global_load_lds(
      (const __attribute__((address_space(1))) uint32_t*)g,
      (__attribute__((address_space(3))) uint32_t*)l, 16, 0, 0);
}

__device__ __forceinline__ void store_out(u16* C, long i, float v) { C[i] = f2bf(v); }
__device__ __forceinline__ void store_out(float* C, long i, float v) { C[i] = v; }

// ---------------- RoPE tables: cos/sin (S_LEN x 64) fp32 ----------------
__global__ void rope_tables_k(float* __restrict__ cosT, float* __restrict__ sinT) {
  int i = blockIdx.x * 256 + threadIdx.x;
  int s = i >> 6, j = i & 63;
  float inv = exp2f(-(float)j * 0.20762050593045983f);  // 10000^(-j/64)
  float ang = (float)s * inv;
  float sv, cv;
  sincosf(ang, &sv, &cv);
  cosT[i] = cv; sinT[i] = sv;
}

// ---------------- fp32 -> bf16 elementwise ----------------
__global__ void cvt_f32_bf16(const float* __restrict__ in, u16* __restrict__ out) {
  long i = ((long)blockIdx.x * 256 + threadIdx.x) * 4;
  float4 v = *(const float4*)(in + i);
  ushort4 o;
  o.x = f2bf(v.x); o.y = f2bf(v.y); o.z = f2bf(v.z); o.w = f2bf(v.w);
  *(ushort4*)(out + i) = o;
}

// -------- fp32 (R x C) -> bf16 transpose (C x R) --------
__global__ void transpose_f32_bf16(const float* __restrict__ in, u16* __restrict__ out,
                                   int R, int C) {
  __shared__ u16 tile[32][33];
  int c0 = blockIdx.x * 32, r0 = blockIdx.y * 32;
  int tx = threadIdx.x, ty = threadIdx.y;  // 32 x 8
  for (int i = 0; i < 32; i += 8)
    tile[ty + i][tx] = f2bf(in[(long)(r0 + ty + i) * C + c0 + tx]);
  __syncthreads();
  for (int i = 0; i < 32; i += 8)
    out[(long)(c0 + ty + i) * R + r0 + tx] = tile[tx][ty + i];
}

// ---------------- GEMM C = A * B^T (bf16 in, fp32 acc, OutT out) ----------------
template <typename OutT>
__global__ __launch_bounds__(256) void gemm_bt(
    const u16* __restrict__ A, const u16* __restrict__ Bt, OutT* __restrict__ C,
    int M, int N, int K) {
  __shared__ __align__(16) __bf16 As[128 * 32];
  __shared__ __align__(16) __bf16 Bs[128 * 32];
  const int tid = threadIdx.x;
  const int wv = tid >> 6;
  const int lane = tid & 63;
  const int quad = lane >> 4;
  const int l16 = lane & 15;
  const int bm = blockIdx.y * 128;
  const int bn = blockIdx.x * 128;

  f32x4 acc[4][4] = {};

  const int arow = wv * 32 + (lane >> 2);
  const int kseg = (lane & 3) * 8;
  const int wm = (wv >> 1) * 64, wn = (wv & 1) * 64;

  for (int k0 = 0; k0 < K; k0 += 32) {
    __syncthreads();
    const u16* ga0 = A + (long)(bm + arow) * K + k0 + kseg;
    llds16(ga0, &As[arow * 32 + kseg]);
    llds16(ga0 + (long)16 * K, &As[(arow + 16) * 32 + kseg]);
    const u16* gb0 = Bt + (long)(bn + arow) * K + k0 + kseg;
    llds16(gb0, &Bs[arow * 32 + kseg]);
    llds16(gb0 + (long)16 * K, &Bs[(arow + 16) * 32 + kseg]);
    __syncthreads();

    bf16x8 af[4], bfr[4];
#pragma unroll
    for (int mt = 0; mt < 4; ++mt)
      af[mt] = *(const bf16x8*)&As[(wm + mt * 16 + l16) * 32 + quad * 8];
#pragma unroll
    for (int nt = 0; nt < 4; ++nt)
      bfr[nt] = *(const bf16x8*)&Bs[(wn + nt * 16 + l16) * 32 + quad * 8];
#pragma unroll
    for (int mt = 0; mt < 4; ++mt)
#pragma unroll
      for (int nt = 0; nt < 4; ++nt)
        acc[mt][nt] = __builtin_amdgcn_mfma_f32_16x16x32_bf16(
            af[mt], bfr[nt], acc[mt][nt], 0, 0, 0);
  }

#pragma unroll
  for (int mt = 0; mt < 4; ++mt)
#pragma unroll
    for (int nt = 0; nt < 4; ++nt)
#pragma unroll
      for (int r = 0; r < 4; ++r) {
        int row = bm + wm + mt * 16 + quad * 4 + r;
        int col = bn + wn + nt * 16 + l16;
        store_out(C, (long)row * N + col, acc[mt][nt][r]);
      }
}

// ---------------- RoPE on Q in place: qkv cols [0,2048) ----------------
__global__ void rope_q_k(u16* __restrict__ qkv, const float* __restrict__ cosT,
                         const float* __restrict__ sinT) {
  long i = (long)blockIdx.x * 256 + threadIdx.x;   // < B*S*16*64
  int j = i & 63;
  long rest = i >> 6;
  int h = rest & 15;
  long bs = rest >> 4;
  int s = bs & (S_LEN - 1);
  long base = bs * QKV_W + h * DHEAD + j;
  float x1 = bf2f(qkv[base]), x2 = bf2f(qkv[base + 64]);
  float c = cosT[s * 64 + j], sn = sinT[s * 64 + j];
  qkv[base] = f2bf(x1 * c - x2 * sn);
  qkv[base + 64] = f2bf(x2 * c + x1 * sn);
}

// ---- RoPE on K: qkv cols [2048,2560) -> Kb (B,4,S,128) ----
__global__ void rope_k_k(const u16* __restrict__ qkv, u16* __restrict__ Kb,
                         const float* __restrict__ cosT, const float* __restrict__ sinT) {
  long i = (long)blockIdx.x * 256 + threadIdx.x;   // < B*S*4*64
  int j = i & 63;
  long rest = i >> 6;
  int g = rest & 3;
  long bs = rest >> 2;
  int s = bs & (S_LEN - 1);
  int b = (int)(bs >> 11);
  long src = bs * QKV_W + 2048 + g * 128 + j;
  float x1 = bf2f(qkv[src]), x2 = bf2f(qkv[src + 64]);
  float c = cosT[s * 64 + j], sn = sinT[s * 64 + j];
  long dst = ((long)(b * NGROUPS + g) * S_LEN + s) * DHEAD + j;
  Kb[dst] = f2bf(x1 * c - x2 * sn);
  Kb[dst + 64] = f2bf(x2 * c + x1 * sn);
}

// ---- V transpose: qkv cols [2560,3072) -> Vt (B,4,128,S) ----
__global__ void v_trans_k(const u16* __restrict__ qkv, u16* __restrict__ Vt) {
  __shared__ u16 tile[32][33];
  int s0 = blockIdx.x * 32, d0 = blockIdx.y * 32;
  int bg = blockIdx.z;
  int b = bg >> 2, g = bg & 3;
  int tx = threadIdx.x, ty = threadIdx.y;
  for (int i = 0; i < 32; i += 8) {
    long s = s0 + ty + i;
    tile[ty + i][tx] = qkv[((long)b * S_LEN + s) * QKV_W + 2560 + g * 128 + d0 + tx];
  }
  __syncthreads();
  for (int i = 0; i < 32; i += 8) {
    int d = d0 + ty + i;
    Vt[((long)(b * NGROUPS + g) * DHEAD + d) * S_LEN + s0 + tx] = tile[tx][ty + i];
  }
}

// ---------------- Flash attention v3: causal-paired tiles ----------------
// grid: (16, NHEADS, B); block 256 = 4 waves; each block runs two 64-row
// q-tiles (t and 31-t) sequentially => 66 chunks/block, perfectly balanced.
__global__ __launch_bounds__(256, 2) void attn_k3(
    const u16* __restrict__ Q,   // qkv (B,S,3072), cols [0,2048) post-rope
    const u16* __restrict__ Kb,  // (B,4,S,128)  post-rope
    const u16* __restrict__ Vt,  // (B,4,128,S)
    u16* __restrict__ ctx) {     // (B,S,16,128)
  __shared__ __align__(16) __bf16 Ks[2][32 * 128];
  __shared__ __align__(16) __bf16 Vts[2][128 * 32];
  __shared__ __align__(16) __bf16 Ps[64 * 32];

  const int h = blockIdx.y, b = blockIdx.z, g = h >> 2;
  const int tid = threadIdx.x, wv = tid >> 6, lane = tid & 63;
  const int quad = lane >> 4, l16 = lane & 15;
  const float SCALE = 0.08838834764831845f;

  const long kbase = (long)(b * NGROUPS + g) * S_LEN * DHEAD;
  const long vbase = (long)(b * NGROUPS + g) * DHEAD * S_LEN;

  const int krow_off = lane >> 4;
  const int vrow_off = lane >> 2;
  const int vchunk = (lane & 3) ^ ((lane >> 2) & 3);
  const int ppos = quad ^ (l16 & 3);

  const __bf16 oneb = (__bf16)((l16 == 0) ? 1.0f : 0.0f);
  const bf16x8 bones = {oneb, oneb, oneb, oneb, oneb, oneb, oneb, oneb};

  for (int pass = 0; pass < 2; ++pass) {
    const int tile = pass == 0 ? (int)blockIdx.x : 31 - (int)blockIdx.x;
    const int q0 = tile * 64;
    const int nch = q0 / 32 + 2;

    // Q fragments in registers: wave rows q0 + wv*16 + l16
    bf16x8 aq[4];
    {
      const u16* qp = Q + (long)(b * S_LEN + q0 + wv * 16 + l16) * QKV_W + h * DHEAD + quad * 8;
#pragma unroll
      for (int ds = 0; ds < 4; ++ds)
        aq[ds] = *(const bf16x8*)(qp + ds * 32);
    }

    // prologue: stage chunk 0 into buffer 0
#pragma unroll
    for (int i = 0; i < 2; ++i) {
      int r0 = wv * 8 + i * 4;
      int row = r0 + krow_off;
      int c = (lane & 15) ^ (row & 15);
      llds16(Kb + kbase + (long)row * DHEAD + c * 8, &Ks[0][r0 * 128 + lane * 8]);
    }
#pragma unroll
    for (int i = 0; i < 2; ++i) {
      int d0 = wv * 32 + i * 16;
      int row = d0 + vrow_off;
      llds16(Vt + vbase + (long)row * S_LEN + vchunk * 8, &Vts[0][d0 * 32 + lane * 8]);
    }
    __syncthreads();

    f32x4 Oacc[9] = {};

    for (int kc = 0; kc < nch; ++kc) {
      const int cur = kc & 1;
      if (kc + 1 < nch) {
        const int nxt = cur ^ 1;
#pragma unroll
        for (int i = 0; i < 2; ++i) {
          int r0 = wv * 8 + i * 4;
          int row = r0 + krow_off;
          int c = (lane & 15) ^ (row & 15);
          llds16(Kb + kbase + (long)((kc + 1) * 32 + row) * DHEAD + c * 8,
                 &Ks[nxt][r0 * 128 + lane * 8]);
        }
#pragma unroll
        for (int i = 0; i < 2; ++i) {
          int d0 = wv * 32 + i * 16;
          int row = d0 + vrow_off;
          llds16(Vt + vbase + (long)row * S_LEN + (kc + 1) * 32 + vchunk * 8,
                 &Vts[nxt][d0 * 32 + lane * 8]);
        }
      }

      // QK^T : 16q x 32k per wave
      f32x4 sacc[2] = {};
#pragma unroll
      for (int ds = 0; ds < 4; ++ds) {
        int pos0 = ((ds * 4 + quad) ^ l16) * 8;
        bf16x8 bk0 = *(const bf16x8*)&Ks[cur][l16 * 128 + pos0];
        bf16x8 bk1 = *(const bf16x8*)&Ks[cur][(16 + l16) * 128 + pos0];
        sacc[0] = __builtin_amdgcn_mfma_f32_16x16x32_bf16(aq[ds], bk0, sacc[0], 0, 0, 0);
        sacc[1] = __builtin_amdgcn_mfma_f32_16x16x32_bf16(aq[ds], bk1, sacc[1], 0, 0, 0);
      }

      // no-max softmax: p = exp(score*scale), masked to 0
#pragma unroll
      for (int r = 0; r < 4; ++r) {
        int qrow = q0 + wv * 16 + quad * 4 + r;
        int key0 = kc * 32 + l16;
        float p0 = (key0 <= qrow) ? __expf(sacc[0][r] * SCALE) : 0.f;
        float p1 = (key0 + 16 <= qrow) ? __expf(sacc[1][r] * SCALE) : 0.f;
        int lrow = quad * 4 + r;
        int c0 = ((l16 >> 3) ^ r) * 8 + (l16 & 7);
        int c1 = (((l16 >> 3) + 2) ^ r) * 8 + (l16 & 7);
        Ps[(wv * 16 + lrow) * 32 + c0] = (__bf16)p0;
        Ps[(wv * 16 + lrow) * 32 + c1] = (__bf16)p1;
      }

      // PV (+ ones-column row-sum into Oacc[8])
      bf16x8 ap = *(const bf16x8*)&Ps[(wv * 16 + l16) * 32 + ppos * 8];
#pragma unroll
      for (int nt = 0; nt < 8; ++nt) {
        bf16x8 bv = *(const bf16x8*)&Vts[cur][(nt * 16 + l16) * 32 + ppos * 8];
        Oacc[nt] = __builtin_amdgcn_mfma_f32_16x16x32_bf16(ap, bv, Oacc[nt], 0, 0, 0);
      }
      Oacc[8] = __builtin_amdgcn_mfma_f32_16x16x32_bf16(ap, bones, Oacc[8], 0, 0, 0);

      __syncthreads();
    }

    // epilogue: broadcast row-sum from lane (quad*16) and store
    float lsum[4];
#pragma unroll
    for (int r = 0; r < 4; ++r)
      lsum[r] = __shfl(Oacc[8][r], quad << 4, 64);

    const long obase = ((long)(b * S_LEN + q0 + wv * 16) * NHEADS + h) * DHEAD;
#pragma unroll
    for (int nt = 0; nt < 8; ++nt)
#pragma unroll
      for (int r = 0; r < 4; ++r) {
        int lrow = quad * 4 + r;
        ctx[obase + (long)lrow * NHEADS * DHEAD + nt * 16 + l16] =
            f2bf(Oacc[nt][r] / lsum[r]);
      }
  }
}

extern "C" void kernel_launch(void* const* d_in, const int* in_sizes, int n_in,
                              void* d_out, int out_size, void* d_ws, size_t ws_size,
                              hipStream_t stream) {
  const float* x   = (const float*)d_in[0];   // (B,S,2048) fp32
  const float* wq  = (const float*)d_in[1];   // (2048, 2048) fp32
  const float* wkv = (const float*)d_in[2];   // (2048, 1024) fp32
  const float* wd  = (const float*)d_in[3];   // (2048, 2048) fp32
  float* out = (float*)d_out;                 // (B,S,2048) fp32

  char* ws = (char*)d_ws;
  float* cosT  = (float*)(ws + 0);             //   524288 B
  float* sinT  = (float*)(ws + 524288);        //   524288 B
  u16* wqkvT = (u16*)(ws + 1048576);           // 12582912 B (3072 x 2048 bf16)
  u16* wdT   = (u16*)(ws + 13631488);          //  8388608 B (2048 x 2048 bf16)
  u16* xb    = (u16*)(ws + 22020096);          // 16777216 B (B*S, 2048) bf16
  u16* qkv   = (u16*)(ws + 38797312);          // 25165824 B (B*S, 3072) bf16
  u16* Kb    = (u16*)(ws + 63963136);          //  4194304 B (B,4,S,128) bf16
  u16* Vt    = (u16*)(ws + 68157440);          //  4194304 B (B,4,128,S) bf16
  u16* ctx   = (u16*)(ws + 72351744);          // 16777216 B (B,S,16,128) bf16
                                               // total 89128960 B

  rope_tables_k<<<512, 256, 0, stream>>>(cosT, sinT);
  cvt_f32_bf16<<<8192, 256, 0, stream>>>(x, xb);
  transpose_f32_bf16<<<dim3(64, 64), dim3(32, 8), 0, stream>>>(wq, wqkvT, 2048, 2048);
  transpose_f32_bf16<<<dim3(32, 64), dim3(32, 8), 0, stream>>>(wkv, wqkvT + (long)2048 * 2048, 2048, 1024);
  transpose_f32_bf16<<<dim3(64, 64), dim3(32, 8), 0, stream>>>(wd, wdT, 2048, 2048);

  // fused QKV projection: (B*S,2048) x (3072,2048)^T -> (B*S,3072)
  gemm_bt<u16><<<dim3(24, 32), 256, 0, stream>>>(xb, wqkvT, qkv, 4096, 3072, 2048);

  rope_q_k<<<16384, 256, 0, stream>>>(qkv, cosT, sinT);
  rope_k_k<<<4096, 256, 0, stream>>>(qkv, Kb, cosT, sinT);
  v_trans_k<<<dim3(64, 4, 8), dim3(32, 8), 0, stream>>>(qkv, Vt);

  attn_k3<<<dim3(16, 16, 2), 256, 0, stream>>>(qkv, Kb, Vt, ctx);

  gemm_bt<float><<<dim3(16, 32), 256, 0, stream>>>(ctx, wdT, out, 4096, 2048, 2048);
}

// Round 5
// 327.418 us; speedup vs baseline: 1.7527x; 1.0086x over previous
//
#include <hip/hip_runtime.h>
#include <hip/hip_bf16.h>
#include <stdint.h>

typedef unsigned short u16;
typedef __bf16 bf16x8 __attribute__((ext_vector_type(8)));
typedef float f32x4 __attribute__((ext_vector_type(4)));

#define S_LEN 2048
#define BATCH 2
#define NHEADS 16
#define NGROUPS 4
#define DHEAD 128
#define QKV_W 3072   // fused projection width: 2048 q + 1024 kv

__device__ __forceinline__ float bf2f(u16 u) {
  union { uint32_t i; float f; } v; v.i = ((uint32_t)u) << 16; return v.f;
}
__device__ __forceinline__ u16 f2bf(float f) {
  union { float f; uint32_t i; } v; v.f = f;
  uint32_t r = v.i + 0x7FFF + ((v.i >> 16) & 1);
  return (u16)(r >> 16);
}
__device__ __forceinline__ void llds16(const void* g, void* l) {
  __builtin_amdgcn_global_load_lds(
      (const __attribute__((address_space(1))) uint32_t*)g,
      (__attribute__((address_space(3))) uint32_t*)l, 16, 0, 0);
}

__device__ __forceinline__ void store_out(u16* C, long i, float v) { C[i] = f2bf(v); }
__device__ __forceinline__ void store_out(float* C, long i, float v) { C[i] = v; }

// ---------------- RoPE tables: cos/sin (S_LEN x 64) fp32 ----------------
__global__ void rope_tables_k(float* __restrict__ cosT, float* __restrict__ sinT) {
  int i = blockIdx.x * 256 + threadIdx.x;
  int s = i >> 6, j = i & 63;
  float inv = exp2f(-(float)j * 0.20762050593045983f);  // 10000^(-j/64)
  float ang = (float)s * inv;
  float sv, cv;
  sincosf(ang, &sv, &cv);
  cosT[i] = cv; sinT[i] = sv;
}

// ---------------- fp32 -> bf16 elementwise ----------------
__global__ void cvt_f32_bf16(const float* __restrict__ in, u16* __restrict__ out) {
  long i = ((long)blockIdx.x * 256 + threadIdx.x) * 4;
  float4 v = *(const float4*)(in + i);
  ushort4 o;
  o.x = f2bf(v.x); o.y = f2bf(v.y); o.z = f2bf(v.z); o.w = f2bf(v.w);
  *(ushort4*)(out + i) = o;
}

// -------- fp32 (R x C) -> bf16 transpose (C x R) --------
__global__ void transpose_f32_bf16(const float* __restrict__ in, u16* __restrict__ out,
                                   int R, int C) {
  __shared__ u16 tile[32][33];
  int c0 = blockIdx.x * 32, r0 = blockIdx.y * 32;
  int tx = threadIdx.x, ty = threadIdx.y;  // 32 x 8
  for (int i = 0; i < 32; i += 8)
    tile[ty + i][tx] = f2bf(in[(long)(r0 + ty + i) * C + c0 + tx]);
  __syncthreads();
  for (int i = 0; i < 32; i += 8)
    out[(long)(c0 + ty + i) * R + r0 + tx] = tile[tx][ty + i];
}

// ---------------- GEMM C = A * B^T (bf16 in, fp32 acc, OutT out) ----------------
template <typename OutT>
__global__ __launch_bounds__(256) void gemm_bt(
    const u16* __restrict__ A, const u16* __restrict__ Bt, OutT* __restrict__ C,
    int M, int N, int K) {
  __shared__ __align__(16) __bf16 As[128 * 32];
  __shared__ __align__(16) __bf16 Bs[128 * 32];
  const int tid = threadIdx.x;
  const int wv = tid >> 6;
  const int lane = tid & 63;
  const int quad = lane >> 4;
  const int l16 = lane & 15;
  const int bm = blockIdx.y * 128;
  const int bn = blockIdx.x * 128;

  f32x4 acc[4][4] = {};

  const int arow = wv * 32 + (lane >> 2);
  const int kseg = (lane & 3) * 8;
  const int wm = (wv >> 1) * 64, wn = (wv & 1) * 64;

  for (int k0 = 0; k0 < K; k0 += 32) {
    __syncthreads();
    const u16* ga0 = A + (long)(bm + arow) * K + k0 + kseg;
    llds16(ga0, &As[arow * 32 + kseg]);
    llds16(ga0 + (long)16 * K, &As[(arow + 16) * 32 + kseg]);
    const u16* gb0 = Bt + (long)(bn + arow) * K + k0 + kseg;
    llds16(gb0, &Bs[arow * 32 + kseg]);
    llds16(gb0 + (long)16 * K, &Bs[(arow + 16) * 32 + kseg]);
    __syncthreads();

    bf16x8 af[4], bfr[4];
#pragma unroll
    for (int mt = 0; mt < 4; ++mt)
      af[mt] = *(const bf16x8*)&As[(wm + mt * 16 + l16) * 32 + quad * 8];
#pragma unroll
    for (int nt = 0; nt < 4; ++nt)
      bfr[nt] = *(const bf16x8*)&Bs[(wn + nt * 16 + l16) * 32 + quad * 8];
#pragma unroll
    for (int mt = 0; mt < 4; ++mt)
#pragma unroll
      for (int nt = 0; nt < 4; ++nt)
        acc[mt][nt] = __builtin_amdgcn_mfma_f32_16x16x32_bf16(
            af[mt], bfr[nt], acc[mt][nt], 0, 0, 0);
  }

#pragma unroll
  for (int mt = 0; mt < 4; ++mt)
#pragma unroll
    for (int nt = 0; nt < 4; ++nt)
#pragma unroll
      for (int r = 0; r < 4; ++r) {
        int row = bm + wm + mt * 16 + quad * 4 + r;
        int col = bn + wn + nt * 16 + l16;
        store_out(C, (long)row * N + col, acc[mt][nt][r]);
      }
}

// ---------------- RoPE on Q in place: qkv cols [0,2048) ----------------
__global__ void rope_q_k(u16* __restrict__ qkv, const float* __restrict__ cosT,
                         const float* __restrict__ sinT) {
  long i = (long)blockIdx.x * 256 + threadIdx.x;   // < B*S*16*64
  int j = i & 63;
  long rest = i >> 6;
  int h = rest & 15;
  long bs = rest >> 4;
  int s = bs & (S_LEN - 1);
  long base = bs * QKV_W + h * DHEAD + j;
  float x1 = bf2f(qkv[base]), x2 = bf2f(qkv[base + 64]);
  float c = cosT[s * 64 + j], sn = sinT[s * 64 + j];
  qkv[base] = f2bf(x1 * c - x2 * sn);
  qkv[base + 64] = f2bf(x2 * c + x1 * sn);
}

// ---- RoPE on K: qkv cols [2048,2560) -> Kb (B,4,S,128) ----
__global__ void rope_k_k(const u16* __restrict__ qkv, u16* __restrict__ Kb,
                         const float* __restrict__ cosT, const float* __restrict__ sinT) {
  long i = (long)blockIdx.x * 256 + threadIdx.x;   // < B*S*4*64
  int j = i & 63;
  long rest = i >> 6;
  int g = rest & 3;
  long bs = rest >> 2;
  int s = bs & (S_LEN - 1);
  int b = (int)(bs >> 11);
  long src = bs * QKV_W + 2048 + g * 128 + j;
  float x1 = bf2f(qkv[src]), x2 = bf2f(qkv[src + 64]);
  float c = cosT[s * 64 + j], sn = sinT[s * 64 + j];
  long dst = ((long)(b * NGROUPS + g) * S_LEN + s) * DHEAD + j;
  Kb[dst] = f2bf(x1 * c - x2 * sn);
  Kb[dst + 64] = f2bf(x2 * c + x1 * sn);
}

// ---- V transpose: qkv cols [2560,3072) -> Vt (B,4,128,S) ----
__global__ void v_trans_k(const u16* __restrict__ qkv, u16* __restrict__ Vt) {
  __shared__ u16 tile[32][33];
  int s0 = blockIdx.x * 32, d0 = blockIdx.y * 32;
  int bg = blockIdx.z;
  int b = bg >> 2, g = bg & 3;
  int tx = threadIdx.x, ty = threadIdx.y;
  for (int i = 0; i < 32; i += 8) {
    long s = s0 + ty + i;
    tile[ty + i][tx] = qkv[((long)b * S_LEN + s) * QKV_W + 2560 + g * 128 + d0 + tx];
  }
  __syncthreads();
  for (int i = 0; i < 32; i += 8) {
    int d = d0 + ty + i;
    Vt[((long)(b * NGROUPS + g) * DHEAD + d) * S_LEN + s0 + tx] = tile[tx][ty + i];
  }
}

// ---------------- Flash attention v4: full grid + anti-correlated tiles ----
// grid: (32, NHEADS, B) = 1024 blocks -> 4 blocks/CU (LDS 36 KB each).
// Co-resident blocks (flat ids +256 apart) share x but differ in y-bit3/z;
// tile = (y&8) ? 31-x : x makes per-CU total work constant (136 chunks)
// under round-robin dispatch. Q in regs; xor-swizzled K/V/P; no-max softmax;
// ones-column row-sum; double-buffered K/V, one barrier/chunk.
__global__ __launch_bounds__(256, 4) void attn_k4(
    const u16* __restrict__ Q,   // qkv (B,S,3072), cols [0,2048) post-rope
    const u16* __restrict__ Kb,  // (B,4,S,128)  post-rope
    const u16* __restrict__ Vt,  // (B,4,128,S)
    u16* __restrict__ ctx) {     // (B,S,16,128)
  __shared__ __align__(16) __bf16 Ks[2][32 * 128];
  __shared__ __align__(16) __bf16 Vts[2][128 * 32];
  __shared__ __align__(16) __bf16 Ps[64 * 32];

  const int h = blockIdx.y, b = blockIdx.z, g = h >> 2;
  const int tid = threadIdx.x, wv = tid >> 6, lane = tid & 63;
  const int quad = lane >> 4, l16 = lane & 15;
  const float SCALE = 0.08838834764831845f;

  const int tile = (h & 8) ? 31 - (int)blockIdx.x : (int)blockIdx.x;
  const int q0 = tile * 64;
  const int nch = q0 / 32 + 2;

  const long kbase = (long)(b * NGROUPS + g) * S_LEN * DHEAD;
  const long vbase = (long)(b * NGROUPS + g) * DHEAD * S_LEN;

  const int krow_off = lane >> 4;
  const int vrow_off = lane >> 2;
  const int vchunk = (lane & 3) ^ ((lane >> 2) & 3);
  const int ppos = quad ^ (l16 & 3);

  const __bf16 oneb = (__bf16)((l16 == 0) ? 1.0f : 0.0f);
  const bf16x8 bones = {oneb, oneb, oneb, oneb, oneb, oneb, oneb, oneb};

  // Q fragments in registers: wave rows q0 + wv*16 + l16
  bf16x8 aq[4];
  {
    const u16* qp = Q + (long)(b * S_LEN + q0 + wv * 16 + l16) * QKV_W + h * DHEAD + quad * 8;
#pragma unroll
    for (int ds = 0; ds < 4; ++ds)
      aq[ds] = *(const bf16x8*)(qp + ds * 32);
  }

  // prologue: stage chunk 0 into buffer 0
#pragma unroll
  for (int i = 0; i < 2; ++i) {
    int r0 = wv * 8 + i * 4;
    int row = r0 + krow_off;
    int c = (lane & 15) ^ (row & 15);
    llds16(Kb + kbase + (long)row * DHEAD + c * 8, &Ks[0][r0 * 128 + lane * 8]);
  }
#pragma unroll
  for (int i = 0; i < 2; ++i) {
    int d0 = wv * 32 + i * 16;
    int row = d0 + vrow_off;
    llds16(Vt + vbase + (long)row * S_LEN + vchunk * 8, &Vts[0][d0 * 32 + lane * 8]);
  }
  __syncthreads();

  f32x4 Oacc[9] = {};

  for (int kc = 0; kc < nch; ++kc) {
    const int cur = kc & 1;
    if (kc + 1 < nch) {
      const int nxt = cur ^ 1;
#pragma unroll
      for (int i = 0; i < 2; ++i) {
        int r0 = wv * 8 + i * 4;
        int row = r0 + krow_off;
        int c = (lane & 15) ^ (row & 15);
        llds16(Kb + kbase + (long)((kc + 1) * 32 + row) * DHEAD + c * 8,
               &Ks[nxt][r0 * 128 + lane * 8]);
      }
#pragma unroll
      for (int i = 0; i < 2; ++i) {
        int d0 = wv * 32 + i * 16;
        int row = d0 + vrow_off;
        llds16(Vt + vbase + (long)row * S_LEN + (kc + 1) * 32 + vchunk * 8,
               &Vts[nxt][d0 * 32 + lane * 8]);
      }
    }

    // QK^T : 16q x 32k per wave
    f32x4 sacc[2] = {};
#pragma unroll
    for (int ds = 0; ds < 4; ++ds) {
      int pos0 = ((ds * 4 + quad) ^ l16) * 8;
      bf16x8 bk0 = *(const bf16x8*)&Ks[cur][l16 * 128 + pos0];
      bf16x8 bk1 = *(const bf16x8*)&Ks[cur][(16 + l16) * 128 + pos0];
      sacc[0] = __builtin_amdgcn_mfma_f32_16x16x32_bf16(aq[ds], bk0, sacc[0], 0, 0, 0);
      sacc[1] = __builtin_amdgcn_mfma_f32_16x16x32_bf16(aq[ds], bk1, sacc[1], 0, 0, 0);
    }

    // no-max softmax: p = exp(score*scale), masked to 0
#pragma unroll
    for (int r = 0; r < 4; ++r) {
      int qrow = q0 + wv * 16 + quad * 4 + r;
      int key0 = kc * 32 + l16;
      float p0 = (key0 <= qrow) ? __expf(sacc[0][r] * SCALE) : 0.f;
      float p1 = (key0 + 16 <= qrow) ? __expf(sacc[1][r] * SCALE) : 0.f;
      int lrow = quad * 4 + r;
      int c0 = ((l16 >> 3) ^ r) * 8 + (l16 & 7);
      int c1 = (((l16 >> 3) + 2) ^ r) * 8 + (l16 & 7);
      Ps[(wv * 16 + lrow) * 32 + c0] = (__bf16)p0;
      Ps[(wv * 16 + lrow) * 32 + c1] = (__bf16)p1;
    }

    // PV (+ ones-column row-sum into Oacc[8])
    bf16x8 ap = *(const bf16x8*)&Ps[(wv * 16 + l16) * 32 + ppos * 8];
#pragma unroll
    for (int nt = 0; nt < 8; ++nt) {
      bf16x8 bv = *(const bf16x8*)&Vts[cur][(nt * 16 + l16) * 32 + ppos * 8];
      Oacc[nt] = __builtin_amdgcn_mfma_f32_16x16x32_bf16(ap, bv, Oacc[nt], 0, 0, 0);
    }
    Oacc[8] = __builtin_amdgcn_mfma_f32_16x16x32_bf16(ap, bones, Oacc[8], 0, 0, 0);

    __syncthreads();
  }

  // epilogue: broadcast row-sum from lane (quad*16) and store
  float lsum[4];
#pragma unroll
  for (int r = 0; r < 4; ++r)
    lsum[r] = __shfl(Oacc[8][r], quad << 4, 64);

  const long obase = ((long)(b * S_LEN + q0 + wv * 16) * NHEADS + h) * DHEAD;
#pragma unroll
  for (int nt = 0; nt < 8; ++nt)
#pragma unroll
    for (int r = 0; r < 4; ++r) {
      int lrow = quad * 4 + r;
      ctx[obase + (long)lrow * NHEADS * DHEAD + nt * 16 + l16] =
          f2bf(Oacc[nt][r] / lsum[r]);
    }
}

extern "C" void kernel_launch(void* const* d_in, const int* in_sizes, int n_in,
                              void* d_out, int out_size, void* d_ws, size_t ws_size,
                              hipStream_t stream) {
  const float* x   = (const float*)d_in[0];   // (B,S,2048) fp32
  const float* wq  = (const float*)d_in[1];   // (2048, 2048) fp32
  const float* wkv = (const float*)d_in[2];   // (2048, 1024) fp32
  const float* wd  = (const float*)d_in[3];   // (2048, 2048) fp32
  float* out = (float*)d_out;                 // (B,S,2048) fp32

  char* ws = (char*)d_ws;
  float* cosT  = (float*)(ws + 0);             //   524288 B
  float* sinT  = (float*)(ws + 524288);        //   524288 B
  u16* wqkvT = (u16*)(ws + 1048576);           // 12582912 B (3072 x 2048 bf16)
  u16* wdT   = (u16*)(ws + 13631488);          //  8388608 B (2048 x 2048 bf16)
  u16* xb    = (u16*)(ws + 22020096);          // 16777216 B (B*S, 2048) bf16
  u16* qkv   = (u16*)(ws + 38797312);          // 25165824 B (B*S, 3072) bf16
  u16* Kb    = (u16*)(ws + 63963136);          //  4194304 B (B,4,S,128) bf16
  u16* Vt    = (u16*)(ws + 68157440);          //  4194304 B (B,4,128,S) bf16
  u16* ctx   = (u16*)(ws + 72351744);          // 16777216 B (B,S,16,128) bf16
                                               // total 89128960 B

  rope_tables_k<<<512, 256, 0, stream>>>(cosT, sinT);
  cvt_f32_bf16<<<8192, 256, 0, stream>>>(x, xb);
  transpose_f32_bf16<<<dim3(64, 64), dim3(32, 8), 0, stream>>>(wq, wqkvT, 2048, 2048);
  transpose_f32_bf16<<<dim3(32, 64), dim3(32, 8), 0, stream>>>(wkv, wqkvT + (long)2048 * 2048, 2048, 1024);
  transpose_f32_bf16<<<dim3(64, 64), dim3(32, 8), 0, stream>>>(wd, wdT, 2048, 2048);

  // fused QKV projection: (B*S,2048) x (3072,2048)^T -> (B*S,3072)
  gemm_bt<u16><<<dim3(24, 32), 256, 0, stream>>>(xb, wqkvT, qkv, 4096, 3072, 2048);

  rope_q_k<<<16384, 256, 0, stream>>>(qkv, cosT, sinT);
  rope_k_k<<<4096, 256, 0, stream>>>(qkv, Kb, cosT, sinT);
  v_trans_k<<<dim3(64, 4, 8), dim3(32, 8), 0, stream>>>(qkv, Vt);

  attn_k4<<<dim3(32, 16, 2), 256, 0, stream>>>(qkv, Kb, Vt, ctx);

  gemm_bt<float><<<dim3(16, 32), 256, 0, stream>>>(ctx, wdT, out, 4096, 2048, 2048);
}

// Round 6
// 317.977 us; speedup vs baseline: 1.8048x; 1.0297x over previous
//
#include <hip/hip_runtime.h>
#include <hip/hip_bf16.h>
#include <stdint.h>

typedef unsigned short u16;
typedef __bf16 bf16x8 __attribute__((ext_vector_type(8)));
typedef float f32x4 __attribute__((ext_vector_type(4)));

#define S_LEN 2048
#define BATCH 2
#define NHEADS 16
#define NGROUPS 4
#define DHEAD 128
#define QKV_W 3072   // fused projection width: 2048 q + 1024 kv

__device__ __forceinline__ float bf2f(u16 u) {
  union { uint32_t i; float f; } v; v.i = ((uint32_t)u) << 16; return v.f;
}
__device__ __forceinline__ u16 f2bf(float f) {
  union { float f; uint32_t i; } v; v.f = f;
  uint32_t r = v.i + 0x7FFF + ((v.i >> 16) & 1);
  return (u16)(r >> 16);
}
__device__ __forceinline__ void llds16(const void* g, void* l) {
  __builtin_amdgcn_global_load_lds(
      (const __attribute__((address_space(1))) uint32_t*)g,
      (__attribute__((address_space(3))) uint32_t*)l, 16, 0, 0);
}

__device__ __forceinline__ void store_out(u16* C, long i, float v) { C[i] = f2bf(v); }
__device__ __forceinline__ void store_out(float* C, long i, float v) { C[i] = v; }

// ---------------- RoPE tables: cos/sin (S_LEN x 64) fp32 ----------------
__global__ void rope_tables_k(float* __restrict__ cosT, float* __restrict__ sinT) {
  int i = blockIdx.x * 256 + threadIdx.x;
  int s = i >> 6, j = i & 63;
  float inv = exp2f(-(float)j * 0.20762050593045983f);  // 10000^(-j/64)
  float ang = (float)s * inv;
  float sv, cv;
  sincosf(ang, &sv, &cv);
  cosT[i] = cv; sinT[i] = sv;
}

// ---------------- fp32 -> bf16 elementwise ----------------
__global__ void cvt_f32_bf16(const float* __restrict__ in, u16* __restrict__ out) {
  long i = ((long)blockIdx.x * 256 + threadIdx.x) * 4;
  float4 v = *(const float4*)(in + i);
  ushort4 o;
  o.x = f2bf(v.x); o.y = f2bf(v.y); o.z = f2bf(v.z); o.w = f2bf(v.w);
  *(ushort4*)(out + i) = o;
}

// -------- fp32 (R x C) -> bf16 transpose (C x R) --------
__global__ void transpose_f32_bf16(const float* __restrict__ in, u16* __restrict__ out,
                                   int R, int C) {
  __shared__ u16 tile[32][33];
  int c0 = blockIdx.x * 32, r0 = blockIdx.y * 32;
  int tx = threadIdx.x, ty = threadIdx.y;  // 32 x 8
  for (int i = 0; i < 32; i += 8)
    tile[ty + i][tx] = f2bf(in[(long)(r0 + ty + i) * C + c0 + tx]);
  __syncthreads();
  for (int i = 0; i < 32; i += 8)
    out[(long)(c0 + ty + i) * R + r0 + tx] = tile[tx][ty + i];
}

// ---------------- GEMM C = A * B^T (bf16 in, fp32 acc, OutT out) ----------------
template <typename OutT>
__global__ __launch_bounds__(256) void gemm_bt(
    const u16* __restrict__ A, const u16* __restrict__ Bt, OutT* __restrict__ C,
    int M, int N, int K) {
  __shared__ __align__(16) __bf16 As[128 * 32];
  __shared__ __align__(16) __bf16 Bs[128 * 32];
  const int tid = threadIdx.x;
  const int wv = tid >> 6;
  const int lane = tid & 63;
  const int quad = lane >> 4;
  const int l16 = lane & 15;
  const int bm = blockIdx.y * 128;
  const int bn = blockIdx.x * 128;

  f32x4 acc[4][4] = {};

  const int arow = wv * 32 + (lane >> 2);
  const int kseg = (lane & 3) * 8;
  const int wm = (wv >> 1) * 64, wn = (wv & 1) * 64;

  for (int k0 = 0; k0 < K; k0 += 32) {
    __syncthreads();
    const u16* ga0 = A + (long)(bm + arow) * K + k0 + kseg;
    llds16(ga0, &As[arow * 32 + kseg]);
    llds16(ga0 + (long)16 * K, &As[(arow + 16) * 32 + kseg]);
    const u16* gb0 = Bt + (long)(bn + arow) * K + k0 + kseg;
    llds16(gb0, &Bs[arow * 32 + kseg]);
    llds16(gb0 + (long)16 * K, &Bs[(arow + 16) * 32 + kseg]);
    __syncthreads();

    bf16x8 af[4], bfr[4];
#pragma unroll
    for (int mt = 0; mt < 4; ++mt)
      af[mt] = *(const bf16x8*)&As[(wm + mt * 16 + l16) * 32 + quad * 8];
#pragma unroll
    for (int nt = 0; nt < 4; ++nt)
      bfr[nt] = *(const bf16x8*)&Bs[(wn + nt * 16 + l16) * 32 + quad * 8];
#pragma unroll
    for (int mt = 0; mt < 4; ++mt)
#pragma unroll
      for (int nt = 0; nt < 4; ++nt)
        acc[mt][nt] = __builtin_amdgcn_mfma_f32_16x16x32_bf16(
            af[mt], bfr[nt], acc[mt][nt], 0, 0, 0);
  }

#pragma unroll
  for (int mt = 0; mt < 4; ++mt)
#pragma unroll
    for (int nt = 0; nt < 4; ++nt)
#pragma unroll
      for (int r = 0; r < 4; ++r) {
        int row = bm + wm + mt * 16 + quad * 4 + r;
        int col = bn + wn + nt * 16 + l16;
        store_out(C, (long)row * N + col, acc[mt][nt][r]);
      }
}

// ---------------- RoPE on Q in place: qkv cols [0,2048) ----------------
__global__ void rope_q_k(u16* __restrict__ qkv, const float* __restrict__ cosT,
                         const float* __restrict__ sinT) {
  long i = (long)blockIdx.x * 256 + threadIdx.x;   // < B*S*16*64
  int j = i & 63;
  long rest = i >> 6;
  int h = rest & 15;
  long bs = rest >> 4;
  int s = bs & (S_LEN - 1);
  long base = bs * QKV_W + h * DHEAD + j;
  float x1 = bf2f(qkv[base]), x2 = bf2f(qkv[base + 64]);
  float c = cosT[s * 64 + j], sn = sinT[s * 64 + j];
  qkv[base] = f2bf(x1 * c - x2 * sn);
  qkv[base + 64] = f2bf(x2 * c + x1 * sn);
}

// ---- RoPE on K: qkv cols [2048,2560) -> Kb (B,4,S,128) ----
__global__ void rope_k_k(const u16* __restrict__ qkv, u16* __restrict__ Kb,
                         const float* __restrict__ cosT, const float* __restrict__ sinT) {
  long i = (long)blockIdx.x * 256 + threadIdx.x;   // < B*S*4*64
  int j = i & 63;
  long rest = i >> 6;
  int g = rest & 3;
  long bs = rest >> 2;
  int s = bs & (S_LEN - 1);
  int b = (int)(bs >> 11);
  long src = bs * QKV_W + 2048 + g * 128 + j;
  float x1 = bf2f(qkv[src]), x2 = bf2f(qkv[src + 64]);
  float c = cosT[s * 64 + j], sn = sinT[s * 64 + j];
  long dst = ((long)(b * NGROUPS + g) * S_LEN + s) * DHEAD + j;
  Kb[dst] = f2bf(x1 * c - x2 * sn);
  Kb[dst + 64] = f2bf(x2 * c + x1 * sn);
}

// ---- V transpose: qkv cols [2560,3072) -> Vt (B,4,128,S) ----
__global__ void v_trans_k(const u16* __restrict__ qkv, u16* __restrict__ Vt) {
  __shared__ u16 tile[32][33];
  int s0 = blockIdx.x * 32, d0 = blockIdx.y * 32;
  int bg = blockIdx.z;
  int b = bg >> 2, g = bg & 3;
  int tx = threadIdx.x, ty = threadIdx.y;
  for (int i = 0; i < 32; i += 8) {
    long s = s0 + ty + i;
    tile[ty + i][tx] = qkv[((long)b * S_LEN + s) * QKV_W + 2560 + g * 128 + d0 + tx];
  }
  __syncthreads();
  for (int i = 0; i < 32; i += 8) {
    int d = d0 + ty + i;
    Vt[((long)(b * NGROUPS + g) * DHEAD + d) * S_LEN + s0 + tx] = tile[tx][ty + i];
  }
}

// ---------------- Flash attention v5: 64-key chunks, paired tiles ----------
// grid: (16, NHEADS, B) = 512 blocks -> 2/CU; each block runs tiles t and
// 31-t sequentially => uniform 33 chunk64s/block (flat concurrency).
// Per wave per chunk: 16 QK MFMA + 18 PV MFMA (2x issue per barrier vs v4).
// Q in regs; K xor16-swizzled; V/P xor8-swizzled; no-max softmax;
// ones-column row-sum; double-buffered K/V; one barrier per chunk.
__global__ __launch_bounds__(256, 2) void attn_k5(
    const u16* __restrict__ Q,   // qkv (B,S,3072), cols [0,2048) post-rope
    const u16* __restrict__ Kb,  // (B,4,S,128)  post-rope
    const u16* __restrict__ Vt,  // (B,4,128,S)
    u16* __restrict__ ctx) {     // (B,S,16,128)
  __shared__ __align__(16) __bf16 Ks[2][64 * 128];   // 32 KB
  __shared__ __align__(16) __bf16 Vts[2][128 * 64];  // 32 KB
  __shared__ __align__(16) __bf16 Ps[64 * 64];       // 8 KB

  const int h = blockIdx.y, b = blockIdx.z, g = h >> 2;
  const int tid = threadIdx.x, wv = tid >> 6, lane = tid & 63;
  const int quad = lane >> 4, l16 = lane & 15;
  const float SCALE = 0.08838834764831845f;

  const long kbase = (long)(b * NGROUPS + g) * S_LEN * DHEAD;
  const long vbase = (long)(b * NGROUPS + g) * DHEAD * S_LEN;

  // K staging: 64 rows x 128 cols; lane covers row (lane>>4) of a 4-row slab,
  // 16B chunk at swizzled pos l16 (holds source chunk l16 ^ (row&15)).
  const int krow_off = lane >> 4;
  // V staging: 128 d-rows x 64 keys; lane covers row (lane>>3) of an 8-row
  // slab, pos (lane&7) holds source chunk (lane&7) ^ (row&7).
  const int vrow_off = lane >> 3;

  const __bf16 oneb = (__bf16)((l16 == 0) ? 1.0f : 0.0f);
  const bf16x8 bones = {oneb, oneb, oneb, oneb, oneb, oneb, oneb, oneb};

  for (int pass = 0; pass < 2; ++pass) {
    const int tile = pass == 0 ? (int)blockIdx.x : 31 - (int)blockIdx.x;
    const int q0 = tile * 64;
    const int nch = tile + 1;   // 64-key chunks

    // Q fragments in registers: wave rows q0 + wv*16 + l16
    bf16x8 aq[4];
    {
      const u16* qp = Q + (long)(b * S_LEN + q0 + wv * 16 + l16) * QKV_W + h * DHEAD + quad * 8;
#pragma unroll
      for (int ds = 0; ds < 4; ++ds)
        aq[ds] = *(const bf16x8*)(qp + ds * 32);
    }

    // prologue: stage chunk 0 into buffer 0
#pragma unroll
    for (int i = 0; i < 4; ++i) {
      int r0 = wv * 16 + i * 4;
      int row = r0 + krow_off;
      int c = l16 ^ (row & 15);
      llds16(Kb + kbase + (long)row * DHEAD + c * 8, &Ks[0][r0 * 128 + lane * 8]);
    }
#pragma unroll
    for (int i = 0; i < 4; ++i) {
      int d0 = wv * 32 + i * 8;
      int row = d0 + vrow_off;
      int c = (lane & 7) ^ (row & 7);
      llds16(Vt + vbase + (long)row * S_LEN + c * 8, &Vts[0][d0 * 64 + lane * 8]);
    }
    __syncthreads();

    f32x4 Oacc[9] = {};

    for (int kc = 0; kc < nch; ++kc) {
      const int cur = kc & 1;
      if (kc + 1 < nch) {
        const int nxt = cur ^ 1;
#pragma unroll
        for (int i = 0; i < 4; ++i) {
          int r0 = wv * 16 + i * 4;
          int row = r0 + krow_off;
          int c = l16 ^ (row & 15);
          llds16(Kb + kbase + (long)((kc + 1) * 64 + row) * DHEAD + c * 8,
                 &Ks[nxt][r0 * 128 + lane * 8]);
        }
#pragma unroll
        for (int i = 0; i < 4; ++i) {
          int d0 = wv * 32 + i * 8;
          int row = d0 + vrow_off;
          int c = (lane & 7) ^ (row & 7);
          llds16(Vt + vbase + (long)row * S_LEN + (kc + 1) * 64 + c * 8,
                 &Vts[nxt][d0 * 64 + lane * 8]);
        }
      }

      // QK^T : 16q x 64k per wave (16 MFMA)
      f32x4 sacc[4] = {};
#pragma unroll
      for (int ds = 0; ds < 4; ++ds) {
        int pos0 = ((ds * 4 + quad) ^ l16) * 8;
#pragma unroll
        for (int nt = 0; nt < 4; ++nt) {
          bf16x8 bk = *(const bf16x8*)&Ks[cur][(nt * 16 + l16) * 128 + pos0];
          sacc[nt] = __builtin_amdgcn_mfma_f32_16x16x32_bf16(aq[ds], bk, sacc[nt], 0, 0, 0);
        }
      }

      // no-max softmax: p = exp(score*scale), masked to 0; write P (xor8)
#pragma unroll
      for (int nt = 0; nt < 4; ++nt)
#pragma unroll
        for (int r = 0; r < 4; ++r) {
          int qrow = q0 + wv * 16 + quad * 4 + r;
          int key = kc * 64 + nt * 16 + l16;
          float p = (key <= qrow) ? __expf(sacc[nt][r] * SCALE) : 0.f;
          int qlocal = quad * 4 + r;
          int chunk = nt * 2 + (l16 >> 3);
          int pos = chunk ^ (qlocal & 7);
          Ps[(wv * 16 + qlocal) * 64 + pos * 8 + (l16 & 7)] = (__bf16)p;
        }

      // PV (+ ones-column row-sum into Oacc[8]): 18 MFMA
      bf16x8 ap[2];
#pragma unroll
      for (int kf = 0; kf < 2; ++kf) {
        int pos = ((kf * 4 + quad) ^ (l16 & 7)) * 8;
        ap[kf] = *(const bf16x8*)&Ps[(wv * 16 + l16) * 64 + pos];
      }
#pragma unroll
      for (int nt = 0; nt < 8; ++nt)
#pragma unroll
        for (int kf = 0; kf < 2; ++kf) {
          int pos = ((kf * 4 + quad) ^ (l16 & 7)) * 8;
          bf16x8 bv = *(const bf16x8*)&Vts[cur][(nt * 16 + l16) * 64 + pos];
          Oacc[nt] = __builtin_amdgcn_mfma_f32_16x16x32_bf16(ap[kf], bv, Oacc[nt], 0, 0, 0);
        }
      Oacc[8] = __builtin_amdgcn_mfma_f32_16x16x32_bf16(ap[0], bones, Oacc[8], 0, 0, 0);
      Oacc[8] = __builtin_amdgcn_mfma_f32_16x16x32_bf16(ap[1], bones, Oacc[8], 0, 0, 0);

      __syncthreads();
    }

    // epilogue: broadcast row-sum from lane (quad*16) and store
    float lsum[4];
#pragma unroll
    for (int r = 0; r < 4; ++r)
      lsum[r] = __shfl(Oacc[8][r], quad << 4, 64);

    const long obase = ((long)(b * S_LEN + q0 + wv * 16) * NHEADS + h) * DHEAD;
#pragma unroll
    for (int nt = 0; nt < 8; ++nt)
#pragma unroll
      for (int r = 0; r < 4; ++r) {
        int lrow = quad * 4 + r;
        ctx[obase + (long)lrow * NHEADS * DHEAD + nt * 16 + l16] =
            f2bf(Oacc[nt][r] / lsum[r]);
      }
  }
}

extern "C" void kernel_launch(void* const* d_in, const int* in_sizes, int n_in,
                              void* d_out, int out_size, void* d_ws, size_t ws_size,
                              hipStream_t stream) {
  const float* x   = (const float*)d_in[0];   // (B,S,2048) fp32
  const float* wq  = (const float*)d_in[1];   // (2048, 2048) fp32
  const float* wkv = (const float*)d_in[2];   // (2048, 1024) fp32
  const float* wd  = (const float*)d_in[3];   // (2048, 2048) fp32
  float* out = (float*)d_out;                 // (B,S,2048) fp32

  char* ws = (char*)d_ws;
  float* cosT  = (float*)(ws + 0);             //   524288 B
  float* sinT  = (float*)(ws + 524288);        //   524288 B
  u16* wqkvT = (u16*)(ws + 1048576);           // 12582912 B (3072 x 2048 bf16)
  u16* wdT   = (u16*)(ws + 13631488);          //  8388608 B (2048 x 2048 bf16)
  u16* xb    = (u16*)(ws + 22020096);          // 16777216 B (B*S, 2048) bf16
  u16* qkv   = (u16*)(ws + 38797312);          // 25165824 B (B*S, 3072) bf16
  u16* Kb    = (u16*)(ws + 63963136);          //  4194304 B (B,4,S,128) bf16
  u16* Vt    = (u16*)(ws + 68157440);          //  4194304 B (B,4,128,S) bf16
  u16* ctx   = (u16*)(ws + 72351744);          // 16777216 B (B,S,16,128) bf16
                                               // total 89128960 B

  rope_tables_k<<<512, 256, 0, stream>>>(cosT, sinT);
  cvt_f32_bf16<<<8192, 256, 0, stream>>>(x, xb);
  transpose_f32_bf16<<<dim3(64, 64), dim3(32, 8), 0, stream>>>(wq, wqkvT, 2048, 2048);
  transpose_f32_bf16<<<dim3(32, 64), dim3(32, 8), 0, stream>>>(wkv, wqkvT + (long)2048 * 2048, 2048, 1024);
  transpose_f32_bf16<<<dim3(64, 64), dim3(32, 8), 0, stream>>>(wd, wdT, 2048, 2048);

  // fused QKV projection: (B*S,2048) x (3072,2048)^T -> (B*S,3072)
  gemm_bt<u16><<<dim3(24, 32), 256, 0, stream>>>(xb, wqkvT, qkv, 4096, 3072, 2048);

  rope_q_k<<<16384, 256, 0, stream>>>(qkv, cosT, sinT);
  rope_k_k<<<4096, 256, 0, stream>>>(qkv, Kb, cosT, sinT);
  v_trans_k<<<dim3(64, 4, 8), dim3(32, 8), 0, stream>>>(qkv, Vt);

  attn_k5<<<dim3(16, 16, 2), 256, 0, stream>>>(qkv, Kb, Vt, ctx);

  gemm_bt<float><<<dim3(16, 32), 256, 0, stream>>>(ctx, wdT, out, 4096, 2048, 2048);
}